// Round 6
// baseline (391.180 us; speedup 1.0000x reference)
//
#include <hip/hip_runtime.h>
#include <hip/hip_bf16.h>

constexpr int Bn  = 4;
constexpr int Sn  = 2048;
constexpr int NIN = 1024;
constexpr int Hn  = 8;
constexpr int DKn = 128;
constexpr int NL  = Hn * DKn;      // 1024
constexpr int Mrows = Bn * Sn;     // 8192
constexpr int KTILES = NIN / 32;   // 32

// Q pre-scale so attention scores need only exp2: p = 2^(q~ . k)
#define QSCL 0.1275429916f         // log2(e)/sqrt(128)

typedef __bf16 bf16x8 __attribute__((ext_vector_type(8)));
typedef float  f32x4  __attribute__((ext_vector_type(4)));

__device__ __forceinline__ unsigned short f2bf(float f) {   // RNE f32->bf16 bits
    unsigned u = __builtin_bit_cast(unsigned, f);
    u += 0x7FFFu + ((u >> 16) & 1u);
    return (unsigned short)(u >> 16);
}
__device__ __forceinline__ unsigned pk2(float lo, float hi) {
    return (unsigned)f2bf(lo) | ((unsigned)f2bf(hi) << 16);
}

__device__ __forceinline__ void stage16(const void* g, void* l) {
    __builtin_amdgcn_global_load_lds(
        (const __attribute__((address_space(1))) unsigned int*)g,
        (__attribute__((address_space(3))) unsigned int*)l,
        16, 0, 0);
}

// ---------- convert x (f32 row-major) -> bf16 swizzled K-panels ----------
__global__ void convert_x(const float* __restrict__ x, unsigned short* __restrict__ Ap)
{
    const int gid = blockIdx.x * 256 + threadIdx.x;
    const int e = gid * 8;
    const int row = e >> 10, k = e & 1023;
    const int tm = row >> 7, r = row & 127;
    const int kc = k >> 5, kk = k & 31;
    const float4 v0 = *(const float4*)&x[e];
    const float4 v1 = *(const float4*)&x[e + 4];
    uint4 w;
    w.x = pk2(v0.x, v0.y); w.y = pk2(v0.z, v0.w);
    w.z = pk2(v1.x, v1.y); w.w = pk2(v1.z, v1.w);
    const size_t tile = (size_t)(tm * KTILES + kc) * 8192;
    const int byte = (r * 64 + kk * 2) ^ ((r & 7) << 4);
    *(uint4*)((char*)Ap + tile + byte) = w;
}

// ---------- convert W (f32 [k][n]) -> bf16 transposed swizzled panels ----------
__global__ void convert_w(const float* __restrict__ Wq, const float* __restrict__ Wk,
                          unsigned short* __restrict__ Bp)
{
    const int tn = blockIdx.x >> 5, kc = blockIdx.x & 31;
    const int t = threadIdx.x;
    const int c = t & 127, kh = (t >> 7) * 16;
    const float* __restrict__ W = (tn < 8) ? Wq : Wk;
    const int ncol = (tn & 7) * 128 + c;
    const int k0 = kc * 32 + kh;
    float v[16];
    #pragma unroll
    for (int j = 0; j < 16; ++j)
        v[j] = W[(size_t)(k0 + j) * NL + ncol];
    uint4 w0, w1;
    w0.x = pk2(v[0], v[1]);  w0.y = pk2(v[2], v[3]);
    w0.z = pk2(v[4], v[5]);  w0.w = pk2(v[6], v[7]);
    w1.x = pk2(v[8], v[9]);  w1.y = pk2(v[10], v[11]);
    w1.z = pk2(v[12], v[13]); w1.w = pk2(v[14], v[15]);
    const size_t tbase = (size_t)blockIdx.x * 8192;
    const int b0 = (c * 64 + kh * 2) ^ ((c & 7) << 4);
    const int b1 = (c * 64 + kh * 2 + 16) ^ ((c & 7) << 4);
    *(uint4*)((char*)Bp + tbase + b0) = w0;
    *(uint4*)((char*)Bp + tbase + b1) = w1;
}

// ---------- fused projection GEMM (bf16 MFMA) + bias + activation -> bf16 Q/K ----------
__global__ __launch_bounds__(256) void gemm_kernel(
    const unsigned short* __restrict__ Ap, const unsigned short* __restrict__ Bp,
    const float* __restrict__ bq, const float* __restrict__ bk,
    unsigned short* __restrict__ Qb, unsigned short* __restrict__ Kb)
{
    __shared__ unsigned short Asm[128 * 32];
    __shared__ unsigned short Bsm[128 * 32];

    const int tid = threadIdx.x;
    const int wave = tid >> 6, lane = tid & 63;
    const int ln = lane & 15, kg = lane >> 4;
    const int wr = wave >> 1, wc = wave & 1;

    const int bid = blockIdx.x;
    const int wg = (bid & 7) * 128 + (bid >> 3);
    const int bm = wg >> 4, bn = wg & 15;

    const unsigned short* At = Ap + (size_t)bm * (KTILES * 4096);
    const unsigned short* Bt = Bp + (size_t)bn * (KTILES * 4096);

    f32x4 acc[4][4];
    #pragma unroll
    for (int m = 0; m < 4; ++m)
        #pragma unroll
        for (int n = 0; n < 4; ++n) acc[m][n] = (f32x4){0.f, 0.f, 0.f, 0.f};

    int aoff[4], boff[4];
    #pragma unroll
    for (int m = 0; m < 4; ++m) {
        const int row = wr * 64 + m * 16 + ln;
        aoff[m] = (row * 64 + kg * 16) ^ ((ln & 7) << 4);
        const int col = wc * 64 + m * 16 + ln;
        boff[m] = (col * 64 + kg * 16) ^ ((ln & 7) << 4);
    }

    for (int kc = 0; kc < KTILES; ++kc) {
        __syncthreads();
        const unsigned short* ga = At + kc * 4096;
        const unsigned short* gb = Bt + kc * 4096;
        stage16(ga + tid * 8,        Asm + tid * 8);
        stage16(ga + 2048 + tid * 8, Asm + 2048 + tid * 8);
        stage16(gb + tid * 8,        Bsm + tid * 8);
        stage16(gb + 2048 + tid * 8, Bsm + 2048 + tid * 8);
        __syncthreads();

        bf16x8 af[4], bfv[4];
        #pragma unroll
        for (int m = 0; m < 4; ++m) af[m] = *(const bf16x8*)((const char*)Asm + aoff[m]);
        #pragma unroll
        for (int n = 0; n < 4; ++n) bfv[n] = *(const bf16x8*)((const char*)Bsm + boff[n]);
        #pragma unroll
        for (int m = 0; m < 4; ++m)
            #pragma unroll
            for (int n = 0; n < 4; ++n)
                acc[m][n] = __builtin_amdgcn_mfma_f32_16x16x32_bf16(af[m], bfv[n], acc[m][n], 0, 0, 0);
    }

    const bool isQ = (bn < 8);
    const float* __restrict__ bias = isQ ? bq : bk;
    unsigned short* __restrict__ outp = isQ ? Qb : Kb;
    const int cbase = (isQ ? bn : bn - 8) * 128 + wc * 64 + (ln & ~3);
    float4 b4[4];
    #pragma unroll
    for (int n = 0; n < 4; ++n) b4[n] = *(const float4*)&bias[cbase + n * 16];
    const int i = ln & 3;

    #pragma unroll
    for (int m = 0; m < 4; ++m) {
        const size_t grow = bm * 128 + wr * 64 + m * 16 + kg * 4 + i;
        #pragma unroll
        for (int n = 0; n < 4; ++n) {
            float a0 = acc[m][n][0], a1 = acc[m][n][1], a2 = acc[m][n][2], a3 = acc[m][n][3];
            float t;
            t = __shfl_xor((i & 1) ? a0 : a1, 1); if (i & 1) a0 = t; else a1 = t;
            t = __shfl_xor((i & 1) ? a2 : a3, 1); if (i & 1) a2 = t; else a3 = t;
            t = __shfl_xor((i & 2) ? a0 : a2, 2); if (i & 2) a0 = t; else a2 = t;
            t = __shfl_xor((i & 2) ? a1 : a3, 2); if (i & 2) a1 = t; else a3 = t;
            a0 += b4[n].x; a1 += b4[n].y; a2 += b4[n].z; a3 += b4[n].w;
            float r0, r1, r2, r3;
            if (isQ) {
                r0 = tanhf(a0) * QSCL; r1 = tanhf(a1) * QSCL;
                r2 = tanhf(a2) * QSCL; r3 = tanhf(a3) * QSCL;
            } else {
                r0 = 1.0f / (1.0f + __expf(-a0)); r1 = 1.0f / (1.0f + __expf(-a1));
                r2 = 1.0f / (1.0f + __expf(-a2)); r3 = 1.0f / (1.0f + __expf(-a3));
            }
            uint2 w; w.x = pk2(r0, r1); w.y = pk2(r2, r3);
            *(uint2*)&outp[grow * NL + cbase + n * 16] = w;
        }
    }
}

// ---------- attention pass 1: row sums L_q = sum_k exp(z_qk) ----------
// Block = 4 waves x 32 fixed queries, streams a 1024-key half. No LDS, no barriers.
// mfma(A=K, B=Q): lane gets 4 scores for query (lane&15) -> exp2 -> scalar accum.
__global__ __launch_bounds__(256) void rowsum_kernel(
    const unsigned short* __restrict__ Qb, const unsigned short* __restrict__ Kb,
    float* __restrict__ Lsum)
{
    const int tid = threadIdx.x;
    const int wave = tid >> 6, lane = tid & 63;
    const int ln15 = lane & 15, lg = lane >> 4;
    const int h = blockIdx.y;
    const int b = blockIdx.z >> 1, kh = blockIdx.z & 1;
    const int q0 = blockIdx.x * 128 + wave * 32;

    bf16x8 qf0[4], qf1[4];          // fixed B-frags: queries q0..q0+15, q0+16..q0+31
    {
        const size_t r0 = ((size_t)(b * Sn + q0 + ln15)) * NL + h * DKn + lg * 8;
        const size_t r1 = r0 + (size_t)16 * NL;
        #pragma unroll
        for (int ks = 0; ks < 4; ++ks) {
            qf0[ks] = *(const bf16x8*)(Qb + r0 + ks * 32);
            qf1[ks] = *(const bf16x8*)(Qb + r1 + ks * 32);
        }
    }

    const unsigned short* kbase = Kb + ((size_t)(b * Sn + kh * 1024)) * NL + h * DKn;
    float rs0 = 0.f, rs1 = 0.f;

    #pragma unroll 2
    for (int step = 0; step < 64; ++step) {
        const unsigned short* kr = kbase + (size_t)(step * 16 + ln15) * NL + lg * 8;
        bf16x8 k0 = *(const bf16x8*)(kr);
        bf16x8 k1 = *(const bf16x8*)(kr + 32);
        bf16x8 k2 = *(const bf16x8*)(kr + 64);
        bf16x8 k3 = *(const bf16x8*)(kr + 96);
        f32x4 a0 = (f32x4){0.f,0.f,0.f,0.f}, a1 = (f32x4){0.f,0.f,0.f,0.f};
        a0 = __builtin_amdgcn_mfma_f32_16x16x32_bf16(k0, qf0[0], a0, 0, 0, 0);
        a1 = __builtin_amdgcn_mfma_f32_16x16x32_bf16(k0, qf1[0], a1, 0, 0, 0);
        a0 = __builtin_amdgcn_mfma_f32_16x16x32_bf16(k1, qf0[1], a0, 0, 0, 0);
        a1 = __builtin_amdgcn_mfma_f32_16x16x32_bf16(k1, qf1[1], a1, 0, 0, 0);
        a0 = __builtin_amdgcn_mfma_f32_16x16x32_bf16(k2, qf0[2], a0, 0, 0, 0);
        a1 = __builtin_amdgcn_mfma_f32_16x16x32_bf16(k2, qf1[2], a1, 0, 0, 0);
        a0 = __builtin_amdgcn_mfma_f32_16x16x32_bf16(k3, qf0[3], a0, 0, 0, 0);
        a1 = __builtin_amdgcn_mfma_f32_16x16x32_bf16(k3, qf1[3], a1, 0, 0, 0);
        rs0 += exp2f(a0[0]) + exp2f(a0[1]) + exp2f(a0[2]) + exp2f(a0[3]);
        rs1 += exp2f(a1[0]) + exp2f(a1[1]) + exp2f(a1[2]) + exp2f(a1[3]);
    }

    // sum over lane-groups (keys) -> full half-row sums for query ln15
    rs0 += __shfl_xor(rs0, 16); rs0 += __shfl_xor(rs0, 32);
    rs1 += __shfl_xor(rs1, 16); rs1 += __shfl_xor(rs1, 32);
    if (lg == 0) {
        float* L = Lsum + (size_t)(b * Hn + h) * Sn;
        atomicAdd(&L[q0 + ln15], rs0);
        atomicAdd(&L[q0 + 16 + ln15], rs1);
    }
}

// ---------- attention pass 2: colsum_k = sum_q exp(z_qk)/L_q ----------
// Block = 4 waves x 32 fixed keys, streams a 1024-query half + L. Register colsums.
__global__ __launch_bounds__(256) void colsum_kernel(
    const unsigned short* __restrict__ Qb, const unsigned short* __restrict__ Kb,
    const float* __restrict__ Lsum, float* __restrict__ colsum)
{
    const int tid = threadIdx.x;
    const int wave = tid >> 6, lane = tid & 63;
    const int ln15 = lane & 15, lg = lane >> 4;
    const int h = blockIdx.y;
    const int b = blockIdx.z >> 1, qh = blockIdx.z & 1;
    const int k0i = blockIdx.x * 128 + wave * 32;

    bf16x8 kf0[4], kf1[4];          // fixed A-frags: keys k0i..+15, +16..+31
    {
        const size_t r0 = ((size_t)(b * Sn + k0i + ln15)) * NL + h * DKn + lg * 8;
        const size_t r1 = r0 + (size_t)16 * NL;
        #pragma unroll
        for (int ks = 0; ks < 4; ++ks) {
            kf0[ks] = *(const bf16x8*)(Kb + r0 + ks * 32);
            kf1[ks] = *(const bf16x8*)(Kb + r1 + ks * 32);
        }
    }

    const unsigned short* qbase = Qb + ((size_t)(b * Sn + qh * 1024)) * NL + h * DKn;
    const float* lrow = Lsum + (size_t)(b * Hn + h) * Sn + qh * 1024;

    f32x4 c0 = (f32x4){0.f,0.f,0.f,0.f}, c1 = (f32x4){0.f,0.f,0.f,0.f};

    #pragma unroll 2
    for (int step = 0; step < 64; ++step) {
        const unsigned short* qr = qbase + (size_t)(step * 16 + ln15) * NL + lg * 8;
        bf16x8 q0 = *(const bf16x8*)(qr);
        bf16x8 q1 = *(const bf16x8*)(qr + 32);
        bf16x8 q2 = *(const bf16x8*)(qr + 64);
        bf16x8 q3 = *(const bf16x8*)(qr + 96);
        const float rv = 1.0f / lrow[step * 16 + ln15];
        f32x4 a0 = (f32x4){0.f,0.f,0.f,0.f}, a1 = (f32x4){0.f,0.f,0.f,0.f};
        a0 = __builtin_amdgcn_mfma_f32_16x16x32_bf16(kf0[0], q0, a0, 0, 0, 0);
        a1 = __builtin_amdgcn_mfma_f32_16x16x32_bf16(kf1[0], q0, a1, 0, 0, 0);
        a0 = __builtin_amdgcn_mfma_f32_16x16x32_bf16(kf0[1], q1, a0, 0, 0, 0);
        a1 = __builtin_amdgcn_mfma_f32_16x16x32_bf16(kf1[1], q1, a1, 0, 0, 0);
        a0 = __builtin_amdgcn_mfma_f32_16x16x32_bf16(kf0[2], q2, a0, 0, 0, 0);
        a1 = __builtin_amdgcn_mfma_f32_16x16x32_bf16(kf1[2], q2, a1, 0, 0, 0);
        a0 = __builtin_amdgcn_mfma_f32_16x16x32_bf16(kf0[3], q3, a0, 0, 0, 0);
        a1 = __builtin_amdgcn_mfma_f32_16x16x32_bf16(kf1[3], q3, a1, 0, 0, 0);
        c0[0] = fmaf(exp2f(a0[0]), rv, c0[0]);
        c0[1] = fmaf(exp2f(a0[1]), rv, c0[1]);
        c0[2] = fmaf(exp2f(a0[2]), rv, c0[2]);
        c0[3] = fmaf(exp2f(a0[3]), rv, c0[3]);
        c1[0] = fmaf(exp2f(a1[0]), rv, c1[0]);
        c1[1] = fmaf(exp2f(a1[1]), rv, c1[1]);
        c1[2] = fmaf(exp2f(a1[2]), rv, c1[2]);
        c1[3] = fmaf(exp2f(a1[3]), rv, c1[3]);
    }

    // sum over ln15 (queries)
    #pragma unroll
    for (int j = 0; j < 4; ++j) {
        c0[j] += __shfl_xor(c0[j], 1); c0[j] += __shfl_xor(c0[j], 2);
        c0[j] += __shfl_xor(c0[j], 4); c0[j] += __shfl_xor(c0[j], 8);
        c1[j] += __shfl_xor(c1[j], 1); c1[j] += __shfl_xor(c1[j], 2);
        c1[j] += __shfl_xor(c1[j], 4); c1[j] += __shfl_xor(c1[j], 8);
    }
    if (ln15 == 0) {
        float* cs = colsum + (size_t)(b * Hn + h) * Sn;
        #pragma unroll
        for (int j = 0; j < 4; ++j) {
            atomicAdd(&cs[k0i + lg * 4 + j], c0[j]);
            atomicAdd(&cs[k0i + 16 + lg * 4 + j], c1[j]);
        }
    }
}

// ---------- final reduce ----------
__global__ void final_kernel(const float* __restrict__ colsum,
                             const float* __restrict__ w_fc,
                             const float* __restrict__ b_fc,
                             float* __restrict__ out)
{
    const int idx = blockIdx.x * 256 + threadIdx.x;
    if (idx >= Bn * Sn) return;
    const int b = idx / Sn, s = idx - b * Sn;
    float accv = b_fc[0];
    #pragma unroll
    for (int h = 0; h < Hn; ++h)
        accv += colsum[((size_t)(b * Hn + h)) * Sn + s] * w_fc[h] * (1.0f / Sn);
    out[idx] = accv;
}

extern "C" void kernel_launch(void* const* d_in, const int* in_sizes, int n_in,
                              void* d_out, int out_size, void* d_ws, size_t ws_size,
                              hipStream_t stream)
{
    const float* x    = (const float*)d_in[0];
    const float* Wq   = (const float*)d_in[1];
    const float* bq   = (const float*)d_in[2];
    const float* Wk   = (const float*)d_in[3];
    const float* bk   = (const float*)d_in[4];
    const float* w_fc = (const float*)d_in[5];
    const float* b_fc = (const float*)d_in[6];
    float* out = (float*)d_out;

    const size_t NE = (size_t)Mrows * NIN;
    unsigned short* Ap = (unsigned short*)d_ws;
    unsigned short* Bp = Ap + NE;
    unsigned short* Qb = Bp + (size_t)NIN * 2048;
    unsigned short* Kb = Qb + (size_t)Mrows * NL;
    float* colsum = (float*)(Kb + (size_t)Mrows * NL);
    float* Lsum = colsum + (size_t)Bn * Hn * Sn;

    // zero colsum + Lsum (contiguous, 512 KB)
    hipMemsetAsync(colsum, 0, (size_t)Bn * Hn * Sn * sizeof(float) * 2, stream);

    convert_x<<<Mrows * NIN / 8 / 256, 256, 0, stream>>>(x, Ap);
    convert_w<<<16 * KTILES, 256, 0, stream>>>(Wq, Wk, Bp);
    gemm_kernel<<<(Mrows / 128) * (2048 / 128), 256, 0, stream>>>(Ap, Bp, bq, bk, Qb, Kb);
    rowsum_kernel<<<dim3(Sn / 128, Hn, Bn * 2), 256, 0, stream>>>(Qb, Kb, Lsum);
    colsum_kernel<<<dim3(Sn / 128, Hn, Bn * 2), 256, 0, stream>>>(Qb, Kb, Lsum, colsum);
    final_kernel<<<(Bn * Sn + 255) / 256, 256, 0, stream>>>(colsum, w_fc, b_fc, out);
}